// Round 1
// baseline (324.583 us; speedup 1.0000x reference)
//
#include <hip/hip_runtime.h>
#include <hip/hip_bf16.h>
#include <stdint.h>

using bf16x8 = __attribute__((ext_vector_type(8))) short;
using f32x4  = __attribute__((ext_vector_type(4))) float;

#define BATCH 64
#define NTOK  4096
#define HD    256
#define HDIM  1024
#define GD    512

__device__ __forceinline__ ushort f2bf(float f) {
  union { __hip_bfloat16 h; ushort u; } cv;
  cv.h = __float2bfloat16(f);
  return cv.u;
}

__device__ __forceinline__ void gload_lds16(const void* gsrc, void* ldst) {
  typedef const __attribute__((address_space(1))) uint32_t* gas_p;
  typedef __attribute__((address_space(3))) uint32_t* las_p;
  __builtin_amdgcn_global_load_lds((gas_p)(uintptr_t)gsrc, (las_p)(uintptr_t)ldst, 16, 0, 0);
}

// ---- W (fi x fo) f32 -> Wt (fo x fi) bf16 (transpose + convert, per-launch) ----
__global__ __launch_bounds__(256) void wtrans_kernel(const float* __restrict__ W,
                                                     ushort* __restrict__ Wt,
                                                     int fi, int fo) {
  __shared__ float tile[32][33];
  int tx = threadIdx.x & 31, ty = threadIdx.x >> 5;  // 32 x 8
  int c0 = blockIdx.x * 32;                          // fo tile
  int r0 = blockIdx.y * 32;                          // fi tile
#pragma unroll
  for (int j = 0; j < 4; ++j)
    tile[ty + j * 8][tx] = W[(size_t)(r0 + ty + j * 8) * fo + (c0 + tx)];
  __syncthreads();
#pragma unroll
  for (int j = 0; j < 4; ++j)
    Wt[(size_t)(c0 + ty + j * 8) * fi + (r0 + tx)] = f2bf(tile[tx][ty + j * 8]);
}

// ---- Hk[b,k,:] = sum_{i<n, cs[b,i]==k} hs[b,i,:]; counts for mk ----
// one block per (b,k); thread t owns dim t; deterministic (no atomics)
__global__ __launch_bounds__(256) void aggregate_kernel(const float* __restrict__ hs,
                                                        const int* __restrict__ cs,
                                                        const int* __restrict__ nptr,
                                                        float* __restrict__ Hk,
                                                        int* __restrict__ counts,
                                                        int K) {
  int b = blockIdx.x / K, k = blockIdx.x % K;
  int t = threadIdx.x;
  int n = *nptr;
  __shared__ int csb[256];
  float acc = 0.f;
  int cnt = 0;
  const float* hsb = hs + (size_t)b * NTOK * HD;
  const int* csrow = cs + (size_t)b * NTOK;
  for (int i0 = 0; i0 < n; i0 += 256) {
    csb[t] = (i0 + t < n) ? csrow[i0 + t] : -1;
    __syncthreads();
    int lim = min(256, n - i0);
    for (int i = 0; i < lim; ++i) {
      if (csb[i] == k) { acc += hsb[(size_t)(i0 + i) * HD + t]; ++cnt; }
    }
    __syncthreads();
  }
  Hk[((size_t)b * K + k) * HD + t] = acc;
  if (t == 0) counts[b * K + k] = cnt;
}

// ---- Ks[b] = max over cs[b, 0:n] ----
__global__ __launch_bounds__(256) void ks_kernel(const int* __restrict__ cs,
                                                 const int* __restrict__ nptr,
                                                 int* __restrict__ Ks) {
  int b = blockIdx.x, t = threadIdx.x;
  int n = *nptr;
  int m = -1;
  const int* csrow = cs + (size_t)b * NTOK;
  for (int i = t; i < n; i += 256) m = max(m, csrow[i]);
  for (int off = 32; off; off >>= 1) m = max(m, __shfl_down(m, off));
  __shared__ int red[4];
  if ((t & 63) == 0) red[t >> 6] = m;
  __syncthreads();
  if (t == 0) {
    int r = red[0];
    for (int i = 1; i < 4; ++i) r = max(r, red[i]);
    Ks[b] = r;
  }
}

// ---- X rows: [Hk | Hk+hn | hn] per batch, bf16, zero-padded to Mpad ----
__global__ __launch_bounds__(256) void buildx_kernel(const float* __restrict__ Hk,
                                                     const float* __restrict__ hs,
                                                     const int* __restrict__ nptr,
                                                     ushort* __restrict__ X,
                                                     int K, int M) {
  int m = blockIdx.x, t = threadIdx.x;
  float v = 0.f;
  if (m < M) {
    int n = *nptr;
    int b = m / (2 * K + 1), r = m % (2 * K + 1);
    float hn = hs[((size_t)b * NTOK + n) * HD + t];
    if (r < K)          v = Hk[((size_t)b * K + r) * HD + t];
    else if (r < 2 * K) v = Hk[((size_t)b * K + (r - K)) * HD + t] + hn;
    else                v = hn;
  }
  X[(size_t)m * HD + t] = f2bf(v);
}

// ---- 128x128x32 bf16 MFMA GEMM, A (M x Kd) row-major, Bt (N x Kd) row-major ----
// fused bias + PReLU, bf16 out (or f32 out, no act, for LAST)
template <bool LAST>
__global__ __launch_bounds__(256) void gemm_kernel(const ushort* __restrict__ A,
                                                   const ushort* __restrict__ Bt,
                                                   const float* __restrict__ bias,
                                                   const float* __restrict__ aptr,
                                                   void* __restrict__ Cout,
                                                   int N, int Kd) {
  __shared__ ushort As[128 * 32];
  __shared__ ushort Bs[128 * 32];
  int tid = threadIdx.x;
  int lane = tid & 63, w = tid >> 6;
  int wr = w >> 1, wc = w & 1;
  int fr = lane & 15, fq = lane >> 4;
  size_t row0 = (size_t)blockIdx.x * 128;
  size_t col0 = (size_t)blockIdx.y * 128;

  const ushort* Abase = A + row0 * (size_t)Kd;
  const ushort* Bbase = Bt + col0 * (size_t)Kd;

  f32x4 acc[4][4] = {};

  // staging: 512 chunks of 16B per tile; this thread serves chunks q0,q1
  int q0 = w * 64 + lane;
  int q1 = (4 + w) * 64 + lane;
  int r0 = q0 >> 2, kc0 = (q0 & 3) * 8;
  int r1 = q1 >> 2, kc1 = (q1 & 3) * 8;

  for (int k0 = 0; k0 < Kd; k0 += 32) {
    gload_lds16(Abase + (size_t)r0 * Kd + k0 + kc0, &As[(w)     * 512]);
    gload_lds16(Abase + (size_t)r1 * Kd + k0 + kc1, &As[(4 + w) * 512]);
    gload_lds16(Bbase + (size_t)r0 * Kd + k0 + kc0, &Bs[(w)     * 512]);
    gload_lds16(Bbase + (size_t)r1 * Kd + k0 + kc1, &Bs[(4 + w) * 512]);
    __syncthreads();  // drains vmcnt before barrier -> LDS ready
    bf16x8 af[4], bfv[4];
#pragma unroll
    for (int m = 0; m < 4; ++m)
      af[m] = *(const bf16x8*)&As[(wr * 64 + m * 16 + fr) * 32 + fq * 8];
#pragma unroll
    for (int nn = 0; nn < 4; ++nn)
      bfv[nn] = *(const bf16x8*)&Bs[(wc * 64 + nn * 16 + fr) * 32 + fq * 8];
#pragma unroll
    for (int m = 0; m < 4; ++m)
#pragma unroll
      for (int nn = 0; nn < 4; ++nn)
        acc[m][nn] = __builtin_amdgcn_mfma_f32_16x16x32_bf16(af[m], bfv[nn], acc[m][nn], 0, 0, 0);
    __syncthreads();  // all reads done before next stage overwrites
  }

  float alpha = 0.f;
  if (!LAST) alpha = aptr[0];
#pragma unroll
  for (int nn = 0; nn < 4; ++nn) {
    size_t col = col0 + wc * 64 + nn * 16 + fr;
    float bv = bias[col];
#pragma unroll
    for (int m = 0; m < 4; ++m) {
      size_t rbase = row0 + wr * 64 + m * 16 + fq * 4;
#pragma unroll
      for (int j = 0; j < 4; ++j) {
        float v = acc[m][nn][j] + bv;
        if (!LAST) {
          v = (v >= 0.f) ? v : alpha * v;
          ((ushort*)Cout)[(rbase + j) * N + col] = f2bf(v);
        } else {
          ((float*)Cout)[(rbase + j) * N + col] = v;
        }
      }
    }
  }
}

// ---- S, G_head/G_last, Ks move logic, G_mask ----
__global__ __launch_bounds__(256) void final_kernel(const float* __restrict__ gs,
                                                    const int* __restrict__ counts,
                                                    const int* __restrict__ Ks,
                                                    float* __restrict__ out,
                                                    int K) {
  int b = blockIdx.x, t = threadIdx.x;
  __shared__ float mk[64];
  __shared__ int sks;
  if (t < K) mk[t] = (counts[b * K + t] > 0) ? 1.f : 0.f;
  if (t == 0) sks = Ks[b];
  __syncthreads();
  int ks = sks;
  bool need = (ks >= 0) && (ks < K - 1);
  const float* g = gs + (size_t)b * (2 * K + 1) * GD;
  float S0 = 0.f, S1 = 0.f;
  for (int k = 0; k < K; ++k) {
    S0 += g[(size_t)k * GD + t] * mk[k];
    S1 += g[(size_t)k * GD + t + 256] * mk[k];
  }
  float gl0 = S0 + g[(size_t)(2 * K) * GD + t];
  float gl1 = S1 + g[(size_t)(2 * K) * GD + t + 256];
  float* G  = out + (size_t)b * (K + 1) * GD;
  float* Gm = out + (size_t)BATCH * (K + 1) * GD + (size_t)b * (K + 1);
  for (int kk = 0; kk <= K; ++kk) {
    float v0, v1;
    if (kk == K)                  { v0 = need ? 0.f : gl0; v1 = need ? 0.f : gl1; }
    else if (need && kk == ks + 1){ v0 = gl0;              v1 = gl1; }
    else {
      v0 = mk[kk] * (S0 - g[(size_t)kk * GD + t]       + g[(size_t)(K + kk) * GD + t]);
      v1 = mk[kk] * (S1 - g[(size_t)kk * GD + t + 256] + g[(size_t)(K + kk) * GD + t + 256]);
    }
    G[(size_t)kk * GD + t]       = v0;
    G[(size_t)kk * GD + t + 256] = v1;
  }
  if (t <= K) Gm[t] = (need && t >= ks + 2) ? 0.f : 1.f;
}

extern "C" void kernel_launch(void* const* d_in, const int* in_sizes, int n_in,
                              void* d_out, int out_size, void* d_ws, size_t ws_size,
                              hipStream_t stream) {
  const float* hs = (const float*)d_in[0];
  const float* W[6]  = {(const float*)d_in[1], (const float*)d_in[4], (const float*)d_in[7],
                        (const float*)d_in[10], (const float*)d_in[13], (const float*)d_in[16]};
  const float* bb[6] = {(const float*)d_in[2], (const float*)d_in[5], (const float*)d_in[8],
                        (const float*)d_in[11], (const float*)d_in[14], (const float*)d_in[17]};
  const float* aa[5] = {(const float*)d_in[3], (const float*)d_in[6], (const float*)d_in[9],
                        (const float*)d_in[12], (const float*)d_in[15]};
  const int* cs   = (const int*)d_in[18];
  const int* nptr = (const int*)d_in[19];
  float* out = (float*)d_out;

  int K = out_size / (BATCH * (GD + 1)) - 1;  // 32 for this instance
  int M = BATCH * (2 * K + 1);                // 4160
  int Mpad = (M + 127) / 128 * 128;           // 4224

  char* base = (char*)d_ws;
  size_t off = 0;
  auto alloc = [&](size_t bytes) {
    char* p = base + off;
    off = (off + bytes + 255) & ~(size_t)255;
    return p;
  };
  ushort* W1t = (ushort*)alloc((size_t)HDIM * HD * 2);
  ushort* W2t = (ushort*)alloc((size_t)HDIM * HDIM * 2);
  ushort* W3t = (ushort*)alloc((size_t)HDIM * HDIM * 2);
  ushort* W4t = (ushort*)alloc((size_t)HDIM * HDIM * 2);
  ushort* W5t = (ushort*)alloc((size_t)GD * HDIM * 2);
  // note: W6 is (HDIM x GD) -> W6t is (GD x HDIM)
  float*  Hk  = (float*)alloc((size_t)BATCH * K * HD * 4);
  int* counts = (int*)alloc((size_t)BATCH * K * 4);
  int* Ksb    = (int*)alloc(BATCH * 4);
  ushort* X   = (ushort*)alloc((size_t)Mpad * HD * 2);
  ushort* Y0  = (ushort*)alloc((size_t)Mpad * HDIM * 2);
  ushort* Y1  = (ushort*)alloc((size_t)Mpad * HDIM * 2);
  float*  gsb = (float*)alloc((size_t)Mpad * GD * 4);
  (void)ws_size; (void)n_in; (void)in_sizes;

  ushort* Wt2345[4] = {W2t, W3t, W4t, nullptr};
  // transposes: W1 (HD x HDIM), W2..W5 (HDIM x HDIM), W6 (HDIM x GD)
  hipLaunchKernelGGL(wtrans_kernel, dim3(HDIM / 32, HD / 32), dim3(256), 0, stream, W[0], W1t, HD, HDIM);
  hipLaunchKernelGGL(wtrans_kernel, dim3(HDIM / 32, HDIM / 32), dim3(256), 0, stream, W[1], W2t, HDIM, HDIM);
  hipLaunchKernelGGL(wtrans_kernel, dim3(HDIM / 32, HDIM / 32), dim3(256), 0, stream, W[2], W3t, HDIM, HDIM);
  hipLaunchKernelGGL(wtrans_kernel, dim3(HDIM / 32, HDIM / 32), dim3(256), 0, stream, W[3], W4t, HDIM, HDIM);
  // need a 5th HDIMxHDIM buffer: reuse alloc after W5t? allocate one more
  ushort* W5bt = (ushort*)alloc((size_t)HDIM * HDIM * 2);
  hipLaunchKernelGGL(wtrans_kernel, dim3(HDIM / 32, HDIM / 32), dim3(256), 0, stream, W[4], W5bt, HDIM, HDIM);
  hipLaunchKernelGGL(wtrans_kernel, dim3(GD / 32, HDIM / 32), dim3(256), 0, stream, W[5], W5t, HDIM, GD);
  ushort* W6t = W5t;  // (GD x HDIM)
  (void)Wt2345;

  hipLaunchKernelGGL(aggregate_kernel, dim3(BATCH * K), dim3(256), 0, stream, hs, cs, nptr, Hk, counts, K);
  hipLaunchKernelGGL(ks_kernel, dim3(BATCH), dim3(256), 0, stream, cs, nptr, Ksb);
  hipLaunchKernelGGL(buildx_kernel, dim3(Mpad), dim3(256), 0, stream, Hk, hs, nptr, X, K, M);

  dim3 blk(256);
  hipLaunchKernelGGL((gemm_kernel<false>), dim3(Mpad / 128, HDIM / 128), blk, 0, stream, X,   W1t,  bb[0], aa[0], (void*)Y0, HDIM, HD);
  hipLaunchKernelGGL((gemm_kernel<false>), dim3(Mpad / 128, HDIM / 128), blk, 0, stream, Y0,  W2t,  bb[1], aa[1], (void*)Y1, HDIM, HDIM);
  hipLaunchKernelGGL((gemm_kernel<false>), dim3(Mpad / 128, HDIM / 128), blk, 0, stream, Y1,  W3t,  bb[2], aa[2], (void*)Y0, HDIM, HDIM);
  hipLaunchKernelGGL((gemm_kernel<false>), dim3(Mpad / 128, HDIM / 128), blk, 0, stream, Y0,  W4t,  bb[3], aa[3], (void*)Y1, HDIM, HDIM);
  hipLaunchKernelGGL((gemm_kernel<false>), dim3(Mpad / 128, HDIM / 128), blk, 0, stream, Y1,  W5bt, bb[4], aa[4], (void*)Y0, HDIM, HDIM);
  hipLaunchKernelGGL((gemm_kernel<true>),  dim3(Mpad / 128, GD / 128),   blk, 0, stream, Y0,  W6t,  bb[5], nullptr, (void*)gsb, GD, HDIM);

  hipLaunchKernelGGL(final_kernel, dim3(BATCH), dim3(256), 0, stream, gsb, counts, Ksb, out, K);
}

// Round 2
// 221.598 us; speedup vs baseline: 1.4647x; 1.4647x over previous
//
#include <hip/hip_runtime.h>
#include <hip/hip_bf16.h>
#include <stdint.h>

using bf16x8 = __attribute__((ext_vector_type(8))) short;
using f32x4  = __attribute__((ext_vector_type(4))) float;

#define BATCH 64
#define NTOK  4096
#define HD    256
#define HDIM  1024
#define GD    512

__device__ __forceinline__ ushort f2bf(float f) {
  union { __hip_bfloat16 h; ushort u; } cv;
  cv.h = __float2bfloat16(f);
  return cv.u;
}

__device__ __forceinline__ void gload_lds16(const void* gsrc, void* ldst) {
  typedef const __attribute__((address_space(1))) uint32_t* gas_p;
  typedef __attribute__((address_space(3))) uint32_t* las_p;
  __builtin_amdgcn_global_load_lds((gas_p)(uintptr_t)gsrc, (las_p)(uintptr_t)ldst, 16, 0, 0);
}

// ---- W (fi x fo) f32 -> Wt (fo x fi) bf16 (transpose + convert, per-launch) ----
__global__ __launch_bounds__(256) void wtrans_kernel(const float* __restrict__ W,
                                                     ushort* __restrict__ Wt,
                                                     int fi, int fo) {
  __shared__ float tile[32][33];
  int tx = threadIdx.x & 31, ty = threadIdx.x >> 5;  // 32 x 8
  int c0 = blockIdx.x * 32;                          // fo tile
  int r0 = blockIdx.y * 32;                          // fi tile
#pragma unroll
  for (int j = 0; j < 4; ++j)
    tile[ty + j * 8][tx] = W[(size_t)(r0 + ty + j * 8) * fo + (c0 + tx)];
  __syncthreads();
#pragma unroll
  for (int j = 0; j < 4; ++j)
    Wt[(size_t)(c0 + ty + j * 8) * fi + (r0 + tx)] = f2bf(tile[tx][ty + j * 8]);
}

// ---- stable bucketing of tokens by cluster id; also Ks = max(cs[0:n]) ----
// one block (256 threads) per batch. Deterministic: fixed stable scheme, no atomics.
__global__ __launch_bounds__(256) void bucket_kernel(const int* __restrict__ cs,
                                                     const int* __restrict__ nptr,
                                                     int* __restrict__ idx,    // [B][NTOK] slots
                                                     int* __restrict__ off,    // [B][K]
                                                     int* __restrict__ cnt,    // [B][K]
                                                     int* __restrict__ Ks,
                                                     int K) {
  int b = blockIdx.x, t = threadIdx.x;
  int n = *nptr;
  __shared__ int csb[NTOK];
  __shared__ int hist[256 * 32];   // per-thread x per-cluster
  __shared__ int btot[32];
  __shared__ int bbase[32];
  const int* csrow = cs + (size_t)b * NTOK;
  int mymax = -1;
  for (int i = t; i < n; i += 256) { int v = csrow[i]; csb[i] = v; mymax = max(mymax, v); }
#pragma unroll
  for (int k = 0; k < 32; ++k) hist[t * 32 + k] = 0;
  __syncthreads();
  int chunkN = (n + 255) >> 8;
  // histogram: thread t owns tokens t, 256+t, ... (fixed scheme)
  for (int c = 0; c < chunkN; ++c) {
    int i = c * 256 + t;
    if (i < n) hist[t * 32 + csb[i]]++;
  }
  __syncthreads();
  // exclusive prefix across threads per bucket (thread k<32 serial over 256 rows; banks distinct)
  if (t < K) {
    int run = 0;
    for (int r = 0; r < 256; ++r) { int tmp = hist[r * 32 + t]; hist[r * 32 + t] = run; run += tmp; }
    btot[t] = run;
  }
  __syncthreads();
  if (t == 0) {
    int base = 0;
    for (int k = 0; k < K; ++k) { bbase[k] = base; base += btot[k]; }
  }
  __syncthreads();
  if (t < K) { off[b * K + t] = bbase[t]; cnt[b * K + t] = btot[t]; }
  // replay: assign stable slots
  int* idxb = idx + (size_t)b * NTOK;
  for (int c = 0; c < chunkN; ++c) {
    int i = c * 256 + t;
    if (i < n) {
      int k = csb[i];
      int s = bbase[k] + hist[t * 32 + k]++;
      idxb[s] = i;
    }
  }
  // Ks reduce
  for (int o2 = 32; o2; o2 >>= 1) mymax = max(mymax, __shfl_down(mymax, o2));
  __shared__ int red[4];
  if ((t & 63) == 0) red[t >> 6] = mymax;
  __syncthreads();
  if (t == 0) {
    int r = red[0];
    for (int i = 1; i < 4; ++i) r = max(r, red[i]);
    Ks[b] = r;
  }
}

// ---- gather-sum per (b,k) over its bucket; fused X-row writes ----
// X rows per batch: [0..K) = Hk, [K..2K) = Hk + hn, [2K] = hn
__global__ __launch_bounds__(256) void aggregate2_kernel(const float* __restrict__ hs,
                                                         const int* __restrict__ idx,
                                                         const int* __restrict__ off,
                                                         const int* __restrict__ cnt,
                                                         const int* __restrict__ nptr,
                                                         ushort* __restrict__ X,
                                                         int K) {
  int b = blockIdx.x / K, k = blockIdx.x % K;
  int t = threadIdx.x;
  int n = *nptr;
  int c = cnt[b * K + k];
  int o = off[b * K + k];
  const float* hsb = hs + (size_t)b * NTOK * HD;
  const int* ids = idx + (size_t)b * NTOK + o;
  __shared__ int sid[256];
  float a0 = 0.f, a1 = 0.f, a2 = 0.f, a3 = 0.f;
  for (int j0 = 0; j0 < c; j0 += 256) {
    __syncthreads();
    if (j0 + t < c) sid[t] = ids[j0 + t];
    __syncthreads();
    int lim = min(256, c - j0);
    int j = 0;
    for (; j + 3 < lim; j += 4) {
      int i0 = sid[j], i1 = sid[j + 1], i2 = sid[j + 2], i3 = sid[j + 3];
      a0 += hsb[(size_t)i0 * HD + t];
      a1 += hsb[(size_t)i1 * HD + t];
      a2 += hsb[(size_t)i2 * HD + t];
      a3 += hsb[(size_t)i3 * HD + t];
    }
    for (; j < lim; ++j) a0 += hsb[(size_t)sid[j] * HD + t];
  }
  float sum = (a0 + a1) + (a2 + a3);
  float hn = hsb[(size_t)n * HD + t];
  int R = 2 * K + 1;
  X[((size_t)b * R + k) * HD + t]     = f2bf(sum);
  X[((size_t)b * R + K + k) * HD + t] = f2bf(sum + hn);
  if (k == 0) X[((size_t)b * R + 2 * K) * HD + t] = f2bf(hn);
}

// ---- 128x128x32 bf16 MFMA GEMM, A (M x Kd) row-major, Bt (N x Kd) row-major ----
// fused bias + PReLU, bf16 out (or f32 out, no act, for LAST)
template <bool LAST>
__global__ __launch_bounds__(256) void gemm_kernel(const ushort* __restrict__ A,
                                                   const ushort* __restrict__ Bt,
                                                   const float* __restrict__ bias,
                                                   const float* __restrict__ aptr,
                                                   void* __restrict__ Cout,
                                                   int N, int Kd) {
  __shared__ ushort As[128 * 32];
  __shared__ ushort Bs[128 * 32];
  int tid = threadIdx.x;
  int lane = tid & 63, w = tid >> 6;
  int wr = w >> 1, wc = w & 1;
  int fr = lane & 15, fq = lane >> 4;
  size_t row0 = (size_t)blockIdx.x * 128;
  size_t col0 = (size_t)blockIdx.y * 128;

  const ushort* Abase = A + row0 * (size_t)Kd;
  const ushort* Bbase = Bt + col0 * (size_t)Kd;

  f32x4 acc[4][4] = {};

  int q0 = w * 64 + lane;
  int q1 = (4 + w) * 64 + lane;
  int r0 = q0 >> 2, kc0 = (q0 & 3) * 8;
  int r1 = q1 >> 2, kc1 = (q1 & 3) * 8;

  for (int k0 = 0; k0 < Kd; k0 += 32) {
    gload_lds16(Abase + (size_t)r0 * Kd + k0 + kc0, &As[(w)     * 512]);
    gload_lds16(Abase + (size_t)r1 * Kd + k0 + kc1, &As[(4 + w) * 512]);
    gload_lds16(Bbase + (size_t)r0 * Kd + k0 + kc0, &Bs[(w)     * 512]);
    gload_lds16(Bbase + (size_t)r1 * Kd + k0 + kc1, &Bs[(4 + w) * 512]);
    __syncthreads();
    bf16x8 af[4], bfv[4];
#pragma unroll
    for (int m = 0; m < 4; ++m)
      af[m] = *(const bf16x8*)&As[(wr * 64 + m * 16 + fr) * 32 + fq * 8];
#pragma unroll
    for (int nn = 0; nn < 4; ++nn)
      bfv[nn] = *(const bf16x8*)&Bs[(wc * 64 + nn * 16 + fr) * 32 + fq * 8];
#pragma unroll
    for (int m = 0; m < 4; ++m)
#pragma unroll
      for (int nn = 0; nn < 4; ++nn)
        acc[m][nn] = __builtin_amdgcn_mfma_f32_16x16x32_bf16(af[m], bfv[nn], acc[m][nn], 0, 0, 0);
    __syncthreads();
  }

  float alpha = 0.f;
  if (!LAST) alpha = aptr[0];
#pragma unroll
  for (int nn = 0; nn < 4; ++nn) {
    size_t col = col0 + wc * 64 + nn * 16 + fr;
    float bv = bias[col];
#pragma unroll
    for (int m = 0; m < 4; ++m) {
      size_t rbase = row0 + wr * 64 + m * 16 + fq * 4;
#pragma unroll
      for (int j = 0; j < 4; ++j) {
        float v = acc[m][nn][j] + bv;
        if (!LAST) {
          v = (v >= 0.f) ? v : alpha * v;
          ((ushort*)Cout)[(rbase + j) * N + col] = f2bf(v);
        } else {
          ((float*)Cout)[(rbase + j) * N + col] = v;
        }
      }
    }
  }
}

// ---- S, G_head/G_last, Ks move logic, G_mask ----
__global__ __launch_bounds__(256) void final_kernel(const float* __restrict__ gs,
                                                    const int* __restrict__ counts,
                                                    const int* __restrict__ Ks,
                                                    float* __restrict__ out,
                                                    int K) {
  int b = blockIdx.x, t = threadIdx.x;
  __shared__ float mk[64];
  __shared__ int sks;
  if (t < K) mk[t] = (counts[b * K + t] > 0) ? 1.f : 0.f;
  if (t == 0) sks = Ks[b];
  __syncthreads();
  int ks = sks;
  bool need = (ks >= 0) && (ks < K - 1);
  const float* g = gs + (size_t)b * (2 * K + 1) * GD;
  float S0 = 0.f, S1 = 0.f;
  for (int k = 0; k < K; ++k) {
    S0 += g[(size_t)k * GD + t] * mk[k];
    S1 += g[(size_t)k * GD + t + 256] * mk[k];
  }
  float gl0 = S0 + g[(size_t)(2 * K) * GD + t];
  float gl1 = S1 + g[(size_t)(2 * K) * GD + t + 256];
  float* G  = out + (size_t)b * (K + 1) * GD;
  float* Gm = out + (size_t)BATCH * (K + 1) * GD + (size_t)b * (K + 1);
  for (int kk = 0; kk <= K; ++kk) {
    float v0, v1;
    if (kk == K)                  { v0 = need ? 0.f : gl0; v1 = need ? 0.f : gl1; }
    else if (need && kk == ks + 1){ v0 = gl0;              v1 = gl1; }
    else {
      v0 = mk[kk] * (S0 - g[(size_t)kk * GD + t]       + g[(size_t)(K + kk) * GD + t]);
      v1 = mk[kk] * (S1 - g[(size_t)kk * GD + t + 256] + g[(size_t)(K + kk) * GD + t + 256]);
    }
    G[(size_t)kk * GD + t]       = v0;
    G[(size_t)kk * GD + t + 256] = v1;
  }
  if (t <= K) Gm[t] = (need && t >= ks + 2) ? 0.f : 1.f;
}

extern "C" void kernel_launch(void* const* d_in, const int* in_sizes, int n_in,
                              void* d_out, int out_size, void* d_ws, size_t ws_size,
                              hipStream_t stream) {
  const float* hs = (const float*)d_in[0];
  const float* W[6]  = {(const float*)d_in[1], (const float*)d_in[4], (const float*)d_in[7],
                        (const float*)d_in[10], (const float*)d_in[13], (const float*)d_in[16]};
  const float* bb[6] = {(const float*)d_in[2], (const float*)d_in[5], (const float*)d_in[8],
                        (const float*)d_in[11], (const float*)d_in[14], (const float*)d_in[17]};
  const float* aa[5] = {(const float*)d_in[3], (const float*)d_in[6], (const float*)d_in[9],
                        (const float*)d_in[12], (const float*)d_in[15]};
  const int* cs   = (const int*)d_in[18];
  const int* nptr = (const int*)d_in[19];
  float* out = (float*)d_out;

  int K = out_size / (BATCH * (GD + 1)) - 1;  // 32 for this instance
  int M = BATCH * (2 * K + 1);                // 4160
  int Mpad = (M + 127) / 128 * 128;           // 4224

  char* base = (char*)d_ws;
  size_t off_b = 0;
  auto alloc = [&](size_t bytes) {
    char* p = base + off_b;
    off_b = (off_b + bytes + 255) & ~(size_t)255;
    return p;
  };
  ushort* W1t  = (ushort*)alloc((size_t)HDIM * HD * 2);
  ushort* W2t  = (ushort*)alloc((size_t)HDIM * HDIM * 2);
  ushort* W3t  = (ushort*)alloc((size_t)HDIM * HDIM * 2);
  ushort* W4t  = (ushort*)alloc((size_t)HDIM * HDIM * 2);
  ushort* W5bt = (ushort*)alloc((size_t)HDIM * HDIM * 2);
  ushort* W6t  = (ushort*)alloc((size_t)GD * HDIM * 2);
  int* idx     = (int*)alloc((size_t)BATCH * NTOK * 4);
  int* offb    = (int*)alloc((size_t)BATCH * K * 4);
  int* cntb    = (int*)alloc((size_t)BATCH * K * 4);
  int* Ksb     = (int*)alloc(BATCH * 4);
  ushort* X    = (ushort*)alloc((size_t)Mpad * HD * 2);
  ushort* Y0   = (ushort*)alloc((size_t)Mpad * HDIM * 2);
  ushort* Y1   = (ushort*)alloc((size_t)Mpad * HDIM * 2);
  float*  gsb  = (float*)alloc((size_t)Mpad * GD * 4);
  (void)ws_size; (void)n_in; (void)in_sizes;

  // weight transposes: W1 (HD x HDIM), W2..W5 (HDIM x HDIM), W6 (HDIM x GD)
  hipLaunchKernelGGL(wtrans_kernel, dim3(HDIM / 32, HD / 32), dim3(256), 0, stream, W[0], W1t, HD, HDIM);
  hipLaunchKernelGGL(wtrans_kernel, dim3(HDIM / 32, HDIM / 32), dim3(256), 0, stream, W[1], W2t, HDIM, HDIM);
  hipLaunchKernelGGL(wtrans_kernel, dim3(HDIM / 32, HDIM / 32), dim3(256), 0, stream, W[2], W3t, HDIM, HDIM);
  hipLaunchKernelGGL(wtrans_kernel, dim3(HDIM / 32, HDIM / 32), dim3(256), 0, stream, W[3], W4t, HDIM, HDIM);
  hipLaunchKernelGGL(wtrans_kernel, dim3(HDIM / 32, HDIM / 32), dim3(256), 0, stream, W[4], W5bt, HDIM, HDIM);
  hipLaunchKernelGGL(wtrans_kernel, dim3(GD / 32, HDIM / 32), dim3(256), 0, stream, W[5], W6t, HDIM, GD);

  hipLaunchKernelGGL(bucket_kernel, dim3(BATCH), dim3(256), 0, stream, cs, nptr, idx, offb, cntb, Ksb, K);
  hipLaunchKernelGGL(aggregate2_kernel, dim3(BATCH * K), dim3(256), 0, stream, hs, idx, offb, cntb, nptr, X, K);
  // zero the pad rows of X (poisoned 0xAA otherwise)
  hipMemsetAsync(X + (size_t)M * HD, 0, (size_t)(Mpad - M) * HD * 2, stream);

  dim3 blk(256);
  hipLaunchKernelGGL((gemm_kernel<false>), dim3(Mpad / 128, HDIM / 128), blk, 0, stream, X,   W1t,  bb[0], aa[0], (void*)Y0, HDIM, HD);
  hipLaunchKernelGGL((gemm_kernel<false>), dim3(Mpad / 128, HDIM / 128), blk, 0, stream, Y0,  W2t,  bb[1], aa[1], (void*)Y1, HDIM, HDIM);
  hipLaunchKernelGGL((gemm_kernel<false>), dim3(Mpad / 128, HDIM / 128), blk, 0, stream, Y1,  W3t,  bb[2], aa[2], (void*)Y0, HDIM, HDIM);
  hipLaunchKernelGGL((gemm_kernel<false>), dim3(Mpad / 128, HDIM / 128), blk, 0, stream, Y0,  W4t,  bb[3], aa[3], (void*)Y1, HDIM, HDIM);
  hipLaunchKernelGGL((gemm_kernel<false>), dim3(Mpad / 128, HDIM / 128), blk, 0, stream, Y1,  W5bt, bb[4], aa[4], (void*)Y0, HDIM, HDIM);
  hipLaunchKernelGGL((gemm_kernel<true>),  dim3(Mpad / 128, GD / 128),   blk, 0, stream, Y0,  W6t,  bb[5], nullptr, (void*)gsb, GD, HDIM);

  hipLaunchKernelGGL(final_kernel, dim3(BATCH), dim3(256), 0, stream, gsb, cntb, Ksb, out, K);
}

// Round 3
// 189.955 us; speedup vs baseline: 1.7087x; 1.1666x over previous
//
#include <hip/hip_runtime.h>
#include <hip/hip_bf16.h>
#include <stdint.h>

using bf16x8 = __attribute__((ext_vector_type(8))) short;
using f32x4  = __attribute__((ext_vector_type(4))) float;

#define BATCH 64
#define NTOK  4096
#define HD    256
#define HDIM  1024
#define GD    512

__device__ __forceinline__ ushort f2bf(float f) {
  union { __hip_bfloat16 h; ushort u; } cv;
  cv.h = __float2bfloat16(f);
  return cv.u;
}

__device__ __forceinline__ void gload_lds16(const void* gsrc, void* ldst) {
  typedef const __attribute__((address_space(1))) uint32_t* gas_p;
  typedef __attribute__((address_space(3))) uint32_t* las_p;
  __builtin_amdgcn_global_load_lds((gas_p)(uintptr_t)gsrc, (las_p)(uintptr_t)ldst, 16, 0, 0);
}

// ---- all 6 weight transposes in one launch: W (fi x fo) f32 -> Wt (fo x fi) bf16 ----
struct WTArgs {
  const float* src[6];
  ushort* dst[6];
  int fi[6];
  int fo[6];
};

__global__ __launch_bounds__(256) void wtrans_kernel(WTArgs a) {
  int z = blockIdx.z;
  int fi = a.fi[z], fo = a.fo[z];
  int c0 = blockIdx.x * 32;  // fo tile
  int r0 = blockIdx.y * 32;  // fi tile
  if (c0 >= fo || r0 >= fi) return;
  const float* W = a.src[z];
  ushort* Wt = a.dst[z];
  __shared__ float tile[32][33];
  int tx = threadIdx.x & 31, ty = threadIdx.x >> 5;  // 32 x 8
#pragma unroll
  for (int j = 0; j < 4; ++j)
    tile[ty + j * 8][tx] = W[(size_t)(r0 + ty + j * 8) * fo + (c0 + tx)];
  __syncthreads();
#pragma unroll
  for (int j = 0; j < 4; ++j)
    Wt[(size_t)(c0 + ty + j * 8) * fi + (r0 + tx)] = f2bf(tile[tx][ty + j * 8]);
}

// ---- stable bucketing of tokens by cluster id; also Ks = max(cs[0:n]) ----
// one block (256 threads) per batch. Deterministic: fixed stable scheme, no atomics.
__global__ __launch_bounds__(256) void bucket_kernel(const int* __restrict__ cs,
                                                     const int* __restrict__ nptr,
                                                     int* __restrict__ idx,    // [B][NTOK] slots
                                                     int* __restrict__ off,    // [B][K]
                                                     int* __restrict__ cnt,    // [B][K]
                                                     int* __restrict__ Ks,
                                                     int K) {
  int b = blockIdx.x, t = threadIdx.x;
  int n = *nptr;
  __shared__ int csb[NTOK];
  __shared__ int hist[256 * 32];   // per-thread x per-cluster
  __shared__ int btot[32];
  __shared__ int bbase[32];
  const int* csrow = cs + (size_t)b * NTOK;
  int mymax = -1;
  for (int i = t; i < n; i += 256) { int v = csrow[i]; csb[i] = v; mymax = max(mymax, v); }
#pragma unroll
  for (int k = 0; k < 32; ++k) hist[t * 32 + k] = 0;
  __syncthreads();
  int chunkN = (n + 255) >> 8;
  for (int c = 0; c < chunkN; ++c) {
    int i = c * 256 + t;
    if (i < n) hist[t * 32 + csb[i]]++;
  }
  __syncthreads();
  if (t < K) {
    int run = 0;
    for (int r = 0; r < 256; ++r) { int tmp = hist[r * 32 + t]; hist[r * 32 + t] = run; run += tmp; }
    btot[t] = run;
  }
  __syncthreads();
  if (t == 0) {
    int base = 0;
    for (int k = 0; k < K; ++k) { bbase[k] = base; base += btot[k]; }
  }
  __syncthreads();
  if (t < K) { off[b * K + t] = bbase[t]; cnt[b * K + t] = btot[t]; }
  int* idxb = idx + (size_t)b * NTOK;
  for (int c = 0; c < chunkN; ++c) {
    int i = c * 256 + t;
    if (i < n) {
      int k = csb[i];
      int s = bbase[k] + hist[t * 32 + k]++;
      idxb[s] = i;
    }
  }
  for (int o2 = 32; o2; o2 >>= 1) mymax = max(mymax, __shfl_down(mymax, o2));
  __shared__ int red[4];
  if ((t & 63) == 0) red[t >> 6] = mymax;
  __syncthreads();
  if (t == 0) {
    int r = red[0];
    for (int i = 1; i < 4; ++i) r = max(r, red[i]);
    Ks[b] = r;
  }
}

// ---- gather-sum per (b,k) over its bucket; fused X-row writes ----
// X rows per batch: [0..K) = Hk, [K..2K) = Hk + hn, [2K] = hn
__global__ __launch_bounds__(256) void aggregate2_kernel(const float* __restrict__ hs,
                                                         const int* __restrict__ idx,
                                                         const int* __restrict__ off,
                                                         const int* __restrict__ cnt,
                                                         const int* __restrict__ nptr,
                                                         ushort* __restrict__ X,
                                                         int K) {
  int b = blockIdx.x / K, k = blockIdx.x % K;
  int t = threadIdx.x;
  int n = *nptr;
  int c = cnt[b * K + k];
  int o = off[b * K + k];
  const float* hsb = hs + (size_t)b * NTOK * HD;
  const int* ids = idx + (size_t)b * NTOK + o;
  __shared__ int sid[256];
  float a0 = 0.f, a1 = 0.f, a2 = 0.f, a3 = 0.f;
  for (int j0 = 0; j0 < c; j0 += 256) {
    __syncthreads();
    if (j0 + t < c) sid[t] = ids[j0 + t];
    __syncthreads();
    int lim = min(256, c - j0);
    int j = 0;
    for (; j + 3 < lim; j += 4) {
      int i0 = sid[j], i1 = sid[j + 1], i2 = sid[j + 2], i3 = sid[j + 3];
      a0 += hsb[(size_t)i0 * HD + t];
      a1 += hsb[(size_t)i1 * HD + t];
      a2 += hsb[(size_t)i2 * HD + t];
      a3 += hsb[(size_t)i3 * HD + t];
    }
    for (; j < lim; ++j) a0 += hsb[(size_t)sid[j] * HD + t];
  }
  float sum = (a0 + a1) + (a2 + a3);
  float hn = hsb[(size_t)n * HD + t];
  int R = 2 * K + 1;
  X[((size_t)b * R + k) * HD + t]     = f2bf(sum);
  X[((size_t)b * R + K + k) * HD + t] = f2bf(sum + hn);
  if (k == 0) X[((size_t)b * R + 2 * K) * HD + t] = f2bf(hn);
}

// ---- 128x64x32 bf16 MFMA GEMM, A (M x Kd) row-major, Bt (N x Kd) row-major ----
// 4 waves, each computes a 64x32 sub-tile (acc[4][2] of 16x16 frags).
// fused bias + PReLU, bf16 out (or f32 out, no act, for LAST)
template <bool LAST>
__global__ __launch_bounds__(256) void gemm_kernel(const ushort* __restrict__ A,
                                                   const ushort* __restrict__ Bt,
                                                   const float* __restrict__ bias,
                                                   const float* __restrict__ aptr,
                                                   void* __restrict__ Cout,
                                                   int N, int Kd) {
  __shared__ ushort As[128 * 32];  // 8 KB
  __shared__ ushort Bs[64 * 32];   // 4 KB
  int tid = threadIdx.x;
  int lane = tid & 63, w = tid >> 6;
  int wr = w >> 1, wc = w & 1;          // wave grid 2x2: rows wr*64, cols wc*32
  int fr = lane & 15, fq = lane >> 4;
  size_t row0 = (size_t)blockIdx.x * 128;
  size_t col0 = (size_t)blockIdx.y * 64;

  const ushort* Abase = A + row0 * (size_t)Kd;
  const ushort* Bbase = Bt + col0 * (size_t)Kd;

  f32x4 acc[4][2] = {};

  // A: 512 16B-chunks (2 per thread); B: 256 16B-chunks (1 per thread)
  int qA0 = w * 64 + lane;
  int qA1 = 256 + w * 64 + lane;
  int rA0 = qA0 >> 2, kA0 = (qA0 & 3) * 8;
  int rA1 = qA1 >> 2, kA1 = (qA1 & 3) * 8;
  int qB = w * 64 + lane;
  int rB = qB >> 2, kB = (qB & 3) * 8;

  for (int k0 = 0; k0 < Kd; k0 += 32) {
    gload_lds16(Abase + (size_t)rA0 * Kd + k0 + kA0, &As[(w)     * 512]);
    gload_lds16(Abase + (size_t)rA1 * Kd + k0 + kA1, &As[(4 + w) * 512]);
    gload_lds16(Bbase + (size_t)rB  * Kd + k0 + kB,  &Bs[(w)     * 512]);
    __syncthreads();  // drains vmcnt before barrier -> LDS ready
    bf16x8 af[4], bfv[2];
#pragma unroll
    for (int m = 0; m < 4; ++m)
      af[m] = *(const bf16x8*)&As[(wr * 64 + m * 16 + fr) * 32 + fq * 8];
#pragma unroll
    for (int nn = 0; nn < 2; ++nn)
      bfv[nn] = *(const bf16x8*)&Bs[(wc * 32 + nn * 16 + fr) * 32 + fq * 8];
#pragma unroll
    for (int m = 0; m < 4; ++m)
#pragma unroll
      for (int nn = 0; nn < 2; ++nn)
        acc[m][nn] = __builtin_amdgcn_mfma_f32_16x16x32_bf16(af[m], bfv[nn], acc[m][nn], 0, 0, 0);
    __syncthreads();  // all reads done before next stage overwrites
  }

  float alpha = 0.f;
  if (!LAST) alpha = aptr[0];
#pragma unroll
  for (int nn = 0; nn < 2; ++nn) {
    size_t col = col0 + wc * 32 + nn * 16 + fr;
    float bv = bias[col];
#pragma unroll
    for (int m = 0; m < 4; ++m) {
      size_t rbase = row0 + wr * 64 + m * 16 + fq * 4;
#pragma unroll
      for (int j = 0; j < 4; ++j) {
        float v = acc[m][nn][j] + bv;
        if (!LAST) {
          v = (v >= 0.f) ? v : alpha * v;
          ((ushort*)Cout)[(rbase + j) * N + col] = f2bf(v);
        } else {
          ((float*)Cout)[(rbase + j) * N + col] = v;
        }
      }
    }
  }
}

// ---- S, G_head/G_last, Ks move logic, G_mask ----
__global__ __launch_bounds__(256) void final_kernel(const float* __restrict__ gs,
                                                    const int* __restrict__ counts,
                                                    const int* __restrict__ Ks,
                                                    float* __restrict__ out,
                                                    int K) {
  int b = blockIdx.x, t = threadIdx.x;
  __shared__ float mk[64];
  __shared__ int sks;
  if (t < K) mk[t] = (counts[b * K + t] > 0) ? 1.f : 0.f;
  if (t == 0) sks = Ks[b];
  __syncthreads();
  int ks = sks;
  bool need = (ks >= 0) && (ks < K - 1);
  const float* g = gs + (size_t)b * (2 * K + 1) * GD;
  float S0 = 0.f, S1 = 0.f;
  for (int k = 0; k < K; ++k) {
    S0 += g[(size_t)k * GD + t] * mk[k];
    S1 += g[(size_t)k * GD + t + 256] * mk[k];
  }
  float gl0 = S0 + g[(size_t)(2 * K) * GD + t];
  float gl1 = S1 + g[(size_t)(2 * K) * GD + t + 256];
  float* G  = out + (size_t)b * (K + 1) * GD;
  float* Gm = out + (size_t)BATCH * (K + 1) * GD + (size_t)b * (K + 1);
  for (int kk = 0; kk <= K; ++kk) {
    float v0, v1;
    if (kk == K)                  { v0 = need ? 0.f : gl0; v1 = need ? 0.f : gl1; }
    else if (need && kk == ks + 1){ v0 = gl0;              v1 = gl1; }
    else {
      v0 = mk[kk] * (S0 - g[(size_t)kk * GD + t]       + g[(size_t)(K + kk) * GD + t]);
      v1 = mk[kk] * (S1 - g[(size_t)kk * GD + t + 256] + g[(size_t)(K + kk) * GD + t + 256]);
    }
    G[(size_t)kk * GD + t]       = v0;
    G[(size_t)kk * GD + t + 256] = v1;
  }
  if (t <= K) Gm[t] = (need && t >= ks + 2) ? 0.f : 1.f;
}

extern "C" void kernel_launch(void* const* d_in, const int* in_sizes, int n_in,
                              void* d_out, int out_size, void* d_ws, size_t ws_size,
                              hipStream_t stream) {
  const float* hs = (const float*)d_in[0];
  const float* W[6]  = {(const float*)d_in[1], (const float*)d_in[4], (const float*)d_in[7],
                        (const float*)d_in[10], (const float*)d_in[13], (const float*)d_in[16]};
  const float* bb[6] = {(const float*)d_in[2], (const float*)d_in[5], (const float*)d_in[8],
                        (const float*)d_in[11], (const float*)d_in[14], (const float*)d_in[17]};
  const float* aa[5] = {(const float*)d_in[3], (const float*)d_in[6], (const float*)d_in[9],
                        (const float*)d_in[12], (const float*)d_in[15]};
  const int* cs   = (const int*)d_in[18];
  const int* nptr = (const int*)d_in[19];
  float* out = (float*)d_out;

  int K = out_size / (BATCH * (GD + 1)) - 1;  // 32 for this instance
  int M = BATCH * (2 * K + 1);                // 4160
  int Mpad = (M + 127) / 128 * 128;           // 4224

  char* base = (char*)d_ws;
  size_t off_b = 0;
  auto alloc = [&](size_t bytes) {
    char* p = base + off_b;
    off_b = (off_b + bytes + 255) & ~(size_t)255;
    return p;
  };
  ushort* W1t  = (ushort*)alloc((size_t)HDIM * HD * 2);
  ushort* W2t  = (ushort*)alloc((size_t)HDIM * HDIM * 2);
  ushort* W3t  = (ushort*)alloc((size_t)HDIM * HDIM * 2);
  ushort* W4t  = (ushort*)alloc((size_t)HDIM * HDIM * 2);
  ushort* W5bt = (ushort*)alloc((size_t)HDIM * HDIM * 2);
  ushort* W6t  = (ushort*)alloc((size_t)GD * HDIM * 2);
  int* idx     = (int*)alloc((size_t)BATCH * NTOK * 4);
  int* offb    = (int*)alloc((size_t)BATCH * K * 4);
  int* cntb    = (int*)alloc((size_t)BATCH * K * 4);
  int* Ksb     = (int*)alloc(BATCH * 4);
  ushort* X    = (ushort*)alloc((size_t)Mpad * HD * 2);
  ushort* Y0   = (ushort*)alloc((size_t)Mpad * HDIM * 2);
  ushort* Y1   = (ushort*)alloc((size_t)Mpad * HDIM * 2);
  float*  gsb  = (float*)alloc((size_t)Mpad * GD * 4);
  (void)ws_size; (void)n_in; (void)in_sizes;

  // all weight transposes in one launch
  WTArgs wa;
  wa.src[0] = W[0]; wa.dst[0] = W1t;  wa.fi[0] = HD;   wa.fo[0] = HDIM;
  wa.src[1] = W[1]; wa.dst[1] = W2t;  wa.fi[1] = HDIM; wa.fo[1] = HDIM;
  wa.src[2] = W[2]; wa.dst[2] = W3t;  wa.fi[2] = HDIM; wa.fo[2] = HDIM;
  wa.src[3] = W[3]; wa.dst[3] = W4t;  wa.fi[3] = HDIM; wa.fo[3] = HDIM;
  wa.src[4] = W[4]; wa.dst[4] = W5bt; wa.fi[4] = HDIM; wa.fo[4] = HDIM;
  wa.src[5] = W[5]; wa.dst[5] = W6t;  wa.fi[5] = HDIM; wa.fo[5] = GD;
  hipLaunchKernelGGL(wtrans_kernel, dim3(32, 32, 6), dim3(256), 0, stream, wa);

  hipLaunchKernelGGL(bucket_kernel, dim3(BATCH), dim3(256), 0, stream, cs, nptr, idx, offb, cntb, Ksb, K);
  hipLaunchKernelGGL(aggregate2_kernel, dim3(BATCH * K), dim3(256), 0, stream, hs, idx, offb, cntb, nptr, X, K);
  // zero the pad rows of X (poisoned 0xAA otherwise)
  hipMemsetAsync(X + (size_t)M * HD, 0, (size_t)(Mpad - M) * HD * 2, stream);

  dim3 blk(256);
  hipLaunchKernelGGL((gemm_kernel<false>), dim3(Mpad / 128, HDIM / 64), blk, 0, stream, X,   W1t,  bb[0], aa[0], (void*)Y0, HDIM, HD);
  hipLaunchKernelGGL((gemm_kernel<false>), dim3(Mpad / 128, HDIM / 64), blk, 0, stream, Y0,  W2t,  bb[1], aa[1], (void*)Y1, HDIM, HDIM);
  hipLaunchKernelGGL((gemm_kernel<false>), dim3(Mpad / 128, HDIM / 64), blk, 0, stream, Y1,  W3t,  bb[2], aa[2], (void*)Y0, HDIM, HDIM);
  hipLaunchKernelGGL((gemm_kernel<false>), dim3(Mpad / 128, HDIM / 64), blk, 0, stream, Y0,  W4t,  bb[3], aa[3], (void*)Y1, HDIM, HDIM);
  hipLaunchKernelGGL((gemm_kernel<false>), dim3(Mpad / 128, HDIM / 64), blk, 0, stream, Y1,  W5bt, bb[4], aa[4], (void*)Y0, HDIM, HDIM);
  hipLaunchKernelGGL((gemm_kernel<true>),  dim3(Mpad / 128, GD / 64),   blk, 0, stream, Y0,  W6t,  bb[5], nullptr, (void*)gsb, GD, HDIM);

  hipLaunchKernelGGL(final_kernel, dim3(BATCH), dim3(256), 0, stream, gsb, cntb, Ksb, out, K);
}

// Round 4
// 155.445 us; speedup vs baseline: 2.0881x; 1.2220x over previous
//
#include <hip/hip_runtime.h>
#include <hip/hip_bf16.h>
#include <stdint.h>

using bf16x8 = __attribute__((ext_vector_type(8))) short;
using f32x4  = __attribute__((ext_vector_type(4))) float;

#define BATCH 64
#define NTOK  4096
#define HD    256
#define HDIM  1024
#define GD    512

__device__ __forceinline__ ushort f2bf(float f) {
  union { __hip_bfloat16 h; ushort u; } cv;
  cv.h = __float2bfloat16(f);
  return cv.u;
}

__device__ __forceinline__ void gload_lds16(const void* gsrc, void* ldst) {
  typedef const __attribute__((address_space(1))) uint32_t* gas_p;
  typedef __attribute__((address_space(3))) uint32_t* las_p;
  __builtin_amdgcn_global_load_lds((gas_p)(uintptr_t)gsrc, (las_p)(uintptr_t)ldst, 16, 0, 0);
}

// ---- all 6 weight transposes in one launch: W (fi x fo) f32 -> Wt (fo x fi) bf16 ----
struct WTArgs {
  const float* src[6];
  ushort* dst[6];
  int fi[6];
  int fo[6];
};

__global__ __launch_bounds__(256) void wtrans_kernel(WTArgs a) {
  int z = blockIdx.z;
  int fi = a.fi[z], fo = a.fo[z];
  int c0 = blockIdx.x * 32;  // fo tile
  int r0 = blockIdx.y * 32;  // fi tile
  if (c0 >= fo || r0 >= fi) return;
  const float* W = a.src[z];
  ushort* Wt = a.dst[z];
  __shared__ float tile[32][33];
  int tx = threadIdx.x & 31, ty = threadIdx.x >> 5;  // 32 x 8
#pragma unroll
  for (int j = 0; j < 4; ++j)
    tile[ty + j * 8][tx] = W[(size_t)(r0 + ty + j * 8) * fo + (c0 + tx)];
  __syncthreads();
#pragma unroll
  for (int j = 0; j < 4; ++j)
    Wt[(size_t)(c0 + ty + j * 8) * fi + (r0 + tx)] = f2bf(tile[tx][ty + j * 8]);
}

// ---- stable bucketing of tokens by cluster id; also Ks = max(cs[0:n]) ----
__global__ __launch_bounds__(256) void bucket_kernel(const int* __restrict__ cs,
                                                     const int* __restrict__ nptr,
                                                     int* __restrict__ idx,    // [B][NTOK] slots
                                                     int* __restrict__ off,    // [B][K]
                                                     int* __restrict__ cnt,    // [B][K]
                                                     int* __restrict__ Ks,
                                                     int K) {
  int b = blockIdx.x, t = threadIdx.x;
  int n = *nptr;
  __shared__ int csb[NTOK];
  __shared__ int hist[256 * 32];   // per-thread x per-cluster
  __shared__ int btot[32];
  __shared__ int bbase[32];
  const int* csrow = cs + (size_t)b * NTOK;
  int mymax = -1;
  for (int i = t; i < n; i += 256) { int v = csrow[i]; csb[i] = v; mymax = max(mymax, v); }
#pragma unroll
  for (int k = 0; k < 32; ++k) hist[t * 32 + k] = 0;
  __syncthreads();
  int chunkN = (n + 255) >> 8;
  for (int c = 0; c < chunkN; ++c) {
    int i = c * 256 + t;
    if (i < n) hist[t * 32 + csb[i]]++;
  }
  __syncthreads();
  if (t < K) {
    int run = 0;
    for (int r = 0; r < 256; ++r) { int tmp = hist[r * 32 + t]; hist[r * 32 + t] = run; run += tmp; }
    btot[t] = run;
  }
  __syncthreads();
  if (t == 0) {
    int base = 0;
    for (int k = 0; k < K; ++k) { bbase[k] = base; base += btot[k]; }
  }
  __syncthreads();
  if (t < K) { off[b * K + t] = bbase[t]; cnt[b * K + t] = btot[t]; }
  int* idxb = idx + (size_t)b * NTOK;
  for (int c = 0; c < chunkN; ++c) {
    int i = c * 256 + t;
    if (i < n) {
      int k = csb[i];
      int s = bbase[k] + hist[t * 32 + k]++;
      idxb[s] = i;
    }
  }
  for (int o2 = 32; o2; o2 >>= 1) mymax = max(mymax, __shfl_down(mymax, o2));
  __shared__ int red[4];
  if ((t & 63) == 0) red[t >> 6] = mymax;
  __syncthreads();
  if (t == 0) {
    int r = red[0];
    for (int i = 1; i < 4; ++i) r = max(r, red[i]);
    Ks[b] = r;
  }
}

// ---- gather-sum per (b,k) over its bucket; fused X-row writes ----
__global__ __launch_bounds__(256) void aggregate2_kernel(const float* __restrict__ hs,
                                                         const int* __restrict__ idx,
                                                         const int* __restrict__ off,
                                                         const int* __restrict__ cnt,
                                                         const int* __restrict__ nptr,
                                                         ushort* __restrict__ X,
                                                         int K) {
  int b = blockIdx.x / K, k = blockIdx.x % K;
  int t = threadIdx.x;
  int n = *nptr;
  int c = cnt[b * K + k];
  int o = off[b * K + k];
  const float* hsb = hs + (size_t)b * NTOK * HD;
  const int* ids = idx + (size_t)b * NTOK + o;
  __shared__ int sid[256];
  float a0 = 0.f, a1 = 0.f, a2 = 0.f, a3 = 0.f;
  for (int j0 = 0; j0 < c; j0 += 256) {
    __syncthreads();
    if (j0 + t < c) sid[t] = ids[j0 + t];
    __syncthreads();
    int lim = min(256, c - j0);
    int j = 0;
    for (; j + 3 < lim; j += 4) {
      int i0 = sid[j], i1 = sid[j + 1], i2 = sid[j + 2], i3 = sid[j + 3];
      a0 += hsb[(size_t)i0 * HD + t];
      a1 += hsb[(size_t)i1 * HD + t];
      a2 += hsb[(size_t)i2 * HD + t];
      a3 += hsb[(size_t)i3 * HD + t];
    }
    for (; j < lim; ++j) a0 += hsb[(size_t)sid[j] * HD + t];
  }
  float sum = (a0 + a1) + (a2 + a3);
  float hn = hsb[(size_t)n * HD + t];
  int R = 2 * K + 1;
  X[((size_t)b * R + k) * HD + t]     = f2bf(sum);
  X[((size_t)b * R + K + k) * HD + t] = f2bf(sum + hn);
  if (k == 0) X[((size_t)b * R + 2 * K) * HD + t] = f2bf(hn);
}

// ---- 128x64x64 bf16 MFMA GEMM, double-buffered 2-phase pipeline ----
// A (M x Kd) row-major, Bt (N x Kd) row-major. 4 waves, each 64x32 out.
// XCD-swizzled 1D grid. fused bias + PReLU (bf16 out) or f32 out for LAST.
template <bool LAST>
__global__ __launch_bounds__(256) void gemm_kernel(const ushort* __restrict__ A,
                                                   const ushort* __restrict__ Bt,
                                                   const float* __restrict__ bias,
                                                   const float* __restrict__ aptr,
                                                   void* __restrict__ Cout,
                                                   int N, int Kd) {
  // [buf][khalf][tile]: A 128x32 per half, B 64x32 per half
  __shared__ ushort As[2][2][128 * 32];  // 32 KB
  __shared__ ushort Bs[2][2][64 * 32];   // 16 KB
  int tid = threadIdx.x;
  int lane = tid & 63, w = tid >> 6;
  int wr = w >> 1, wc = w & 1;          // wave grid 2x2: rows wr*64, cols wc*32
  int fr = lane & 15, fq = lane >> 4;

  // bijective XCD swizzle (m204), col-fast decomposition so each XCD's
  // contiguous chunk covers few A-panels x all cols (fits per-XCD L2)
  int nwg = gridDim.x;
  int flat = blockIdx.x;
  int q8 = nwg >> 3, r8 = nwg & 7;
  int xcd = flat & 7, loc = flat >> 3;
  int swz = (xcd < r8 ? xcd * (q8 + 1) : r8 * (q8 + 1) + (xcd - r8) * q8) + loc;
  int NC = N >> 6;
  int brow = swz / NC, bcol = swz % NC;

  size_t row0 = (size_t)brow * 128;
  size_t col0 = (size_t)bcol * 64;

  const ushort* Abase = A + row0 * (size_t)Kd;
  const ushort* Bbase = Bt + col0 * (size_t)Kd;

  f32x4 acc[4][2] = {};

  // staging geometry (per 32-k half): A = 512 chunks of 16B (2/thread),
  // B = 256 chunks (1/thread). chunk q -> row q>>2, kcol (q&3)*8
  int qA0 = w * 64 + lane;
  int qA1 = 256 + w * 64 + lane;
  int rA0 = qA0 >> 2, kA0 = (qA0 & 3) * 8;
  int rA1 = qA1 >> 2, kA1 = (qA1 & 3) * 8;
  int rB = qA0 >> 2, kB = (qA0 & 3) * 8;

  auto stage = [&](int buf, int k0) {
#pragma unroll
    for (int h = 0; h < 2; ++h) {
      int kh = k0 + h * 32;
      gload_lds16(Abase + (size_t)rA0 * Kd + kh + kA0, &As[buf][h][(w)     * 512]);
      gload_lds16(Abase + (size_t)rA1 * Kd + kh + kA1, &As[buf][h][(4 + w) * 512]);
      gload_lds16(Bbase + (size_t)rB  * Kd + kh + kB,  &Bs[buf][h][(w)     * 512]);
    }
  };

  int nt = Kd >> 6;
  int cur = 0;
  stage(0, 0);
  __syncthreads();
  for (int t = 0; t < nt; ++t) {
    if (t + 1 < nt) stage(cur ^ 1, (t + 1) * 64);
    bf16x8 af[2][4], bfv[2][2];
#pragma unroll
    for (int h = 0; h < 2; ++h) {
#pragma unroll
      for (int m = 0; m < 4; ++m)
        af[h][m] = *(const bf16x8*)&As[cur][h][(wr * 64 + m * 16 + fr) * 32 + fq * 8];
#pragma unroll
      for (int nn = 0; nn < 2; ++nn)
        bfv[h][nn] = *(const bf16x8*)&Bs[cur][h][(wc * 32 + nn * 16 + fr) * 32 + fq * 8];
    }
#pragma unroll
    for (int h = 0; h < 2; ++h)
#pragma unroll
      for (int m = 0; m < 4; ++m)
#pragma unroll
        for (int nn = 0; nn < 2; ++nn)
          acc[m][nn] = __builtin_amdgcn_mfma_f32_16x16x32_bf16(af[h][m], bfv[h][nn], acc[m][nn], 0, 0, 0);
    __syncthreads();  // joins waves; drains the prefetch that overlapped compute
    cur ^= 1;
  }

  float alpha = 0.f;
  if (!LAST) alpha = aptr[0];
#pragma unroll
  for (int nn = 0; nn < 2; ++nn) {
    size_t col = col0 + wc * 32 + nn * 16 + fr;
    float bv = bias[col];
#pragma unroll
    for (int m = 0; m < 4; ++m) {
      size_t rbase = row0 + wr * 64 + m * 16 + fq * 4;
#pragma unroll
      for (int j = 0; j < 4; ++j) {
        float v = acc[m][nn][j] + bv;
        if (!LAST) {
          v = (v >= 0.f) ? v : alpha * v;
          ((ushort*)Cout)[(rbase + j) * N + col] = f2bf(v);
        } else {
          ((float*)Cout)[(rbase + j) * N + col] = v;
        }
      }
    }
  }
}

// ---- S, G_head/G_last, Ks move logic, G_mask ----
__global__ __launch_bounds__(256) void final_kernel(const float* __restrict__ gs,
                                                    const int* __restrict__ counts,
                                                    const int* __restrict__ Ks,
                                                    float* __restrict__ out,
                                                    int K) {
  int b = blockIdx.x, t = threadIdx.x;
  __shared__ float mk[64];
  __shared__ int sks;
  if (t < K) mk[t] = (counts[b * K + t] > 0) ? 1.f : 0.f;
  if (t == 0) sks = Ks[b];
  __syncthreads();
  int ks = sks;
  bool need = (ks >= 0) && (ks < K - 1);
  const float* g = gs + (size_t)b * (2 * K + 1) * GD;
  float S0 = 0.f, S1 = 0.f;
  for (int k = 0; k < K; ++k) {
    S0 += g[(size_t)k * GD + t] * mk[k];
    S1 += g[(size_t)k * GD + t + 256] * mk[k];
  }
  float gl0 = S0 + g[(size_t)(2 * K) * GD + t];
  float gl1 = S1 + g[(size_t)(2 * K) * GD + t + 256];
  float* G  = out + (size_t)b * (K + 1) * GD;
  float* Gm = out + (size_t)BATCH * (K + 1) * GD + (size_t)b * (K + 1);
  for (int kk = 0; kk <= K; ++kk) {
    float v0, v1;
    if (kk == K)                  { v0 = need ? 0.f : gl0; v1 = need ? 0.f : gl1; }
    else if (need && kk == ks + 1){ v0 = gl0;              v1 = gl1; }
    else {
      v0 = mk[kk] * (S0 - g[(size_t)kk * GD + t]       + g[(size_t)(K + kk) * GD + t]);
      v1 = mk[kk] * (S1 - g[(size_t)kk * GD + t + 256] + g[(size_t)(K + kk) * GD + t + 256]);
    }
    G[(size_t)kk * GD + t]       = v0;
    G[(size_t)kk * GD + t + 256] = v1;
  }
  if (t <= K) Gm[t] = (need && t >= ks + 2) ? 0.f : 1.f;
}

extern "C" void kernel_launch(void* const* d_in, const int* in_sizes, int n_in,
                              void* d_out, int out_size, void* d_ws, size_t ws_size,
                              hipStream_t stream) {
  const float* hs = (const float*)d_in[0];
  const float* W[6]  = {(const float*)d_in[1], (const float*)d_in[4], (const float*)d_in[7],
                        (const float*)d_in[10], (const float*)d_in[13], (const float*)d_in[16]};
  const float* bb[6] = {(const float*)d_in[2], (const float*)d_in[5], (const float*)d_in[8],
                        (const float*)d_in[11], (const float*)d_in[14], (const float*)d_in[17]};
  const float* aa[5] = {(const float*)d_in[3], (const float*)d_in[6], (const float*)d_in[9],
                        (const float*)d_in[12], (const float*)d_in[15]};
  const int* cs   = (const int*)d_in[18];
  const int* nptr = (const int*)d_in[19];
  float* out = (float*)d_out;

  int K = out_size / (BATCH * (GD + 1)) - 1;  // 32 for this instance
  int M = BATCH * (2 * K + 1);                // 4160
  int Mpad = (M + 127) / 128 * 128;           // 4224

  char* base = (char*)d_ws;
  size_t off_b = 0;
  auto alloc = [&](size_t bytes) {
    char* p = base + off_b;
    off_b = (off_b + bytes + 255) & ~(size_t)255;
    return p;
  };
  ushort* W1t  = (ushort*)alloc((size_t)HDIM * HD * 2);
  ushort* W2t  = (ushort*)alloc((size_t)HDIM * HDIM * 2);
  ushort* W3t  = (ushort*)alloc((size_t)HDIM * HDIM * 2);
  ushort* W4t  = (ushort*)alloc((size_t)HDIM * HDIM * 2);
  ushort* W5bt = (ushort*)alloc((size_t)HDIM * HDIM * 2);
  ushort* W6t  = (ushort*)alloc((size_t)GD * HDIM * 2);
  int* idx     = (int*)alloc((size_t)BATCH * NTOK * 4);
  int* offb    = (int*)alloc((size_t)BATCH * K * 4);
  int* cntb    = (int*)alloc((size_t)BATCH * K * 4);
  int* Ksb     = (int*)alloc(BATCH * 4);
  ushort* X    = (ushort*)alloc((size_t)Mpad * HD * 2);
  ushort* Y0   = (ushort*)alloc((size_t)Mpad * HDIM * 2);
  ushort* Y1   = (ushort*)alloc((size_t)Mpad * HDIM * 2);
  float*  gsb  = (float*)alloc((size_t)Mpad * GD * 4);
  (void)ws_size; (void)n_in; (void)in_sizes;

  // all weight transposes in one launch
  WTArgs wa;
  wa.src[0] = W[0]; wa.dst[0] = W1t;  wa.fi[0] = HD;   wa.fo[0] = HDIM;
  wa.src[1] = W[1]; wa.dst[1] = W2t;  wa.fi[1] = HDIM; wa.fo[1] = HDIM;
  wa.src[2] = W[2]; wa.dst[2] = W3t;  wa.fi[2] = HDIM; wa.fo[2] = HDIM;
  wa.src[3] = W[3]; wa.dst[3] = W4t;  wa.fi[3] = HDIM; wa.fo[3] = HDIM;
  wa.src[4] = W[4]; wa.dst[4] = W5bt; wa.fi[4] = HDIM; wa.fo[4] = HDIM;
  wa.src[5] = W[5]; wa.dst[5] = W6t;  wa.fi[5] = HDIM; wa.fo[5] = GD;
  hipLaunchKernelGGL(wtrans_kernel, dim3(32, 32, 6), dim3(256), 0, stream, wa);

  hipLaunchKernelGGL(bucket_kernel, dim3(BATCH), dim3(256), 0, stream, cs, nptr, idx, offb, cntb, Ksb, K);
  hipLaunchKernelGGL(aggregate2_kernel, dim3(BATCH * K), dim3(256), 0, stream, hs, idx, offb, cntb, nptr, X, K);
  // zero the pad rows of X (poisoned 0xAA otherwise)
  hipMemsetAsync(X + (size_t)M * HD, 0, (size_t)(Mpad - M) * HD * 2, stream);

  dim3 blk(256);
  int NR = Mpad / 128;
  hipLaunchKernelGGL((gemm_kernel<false>), dim3(NR * (HDIM / 64)), blk, 0, stream, X,   W1t,  bb[0], aa[0], (void*)Y0, HDIM, HD);
  hipLaunchKernelGGL((gemm_kernel<false>), dim3(NR * (HDIM / 64)), blk, 0, stream, Y0,  W2t,  bb[1], aa[1], (void*)Y1, HDIM, HDIM);
  hipLaunchKernelGGL((gemm_kernel<false>), dim3(NR * (HDIM / 64)), blk, 0, stream, Y1,  W3t,  bb[2], aa[2], (void*)Y0, HDIM, HDIM);
  hipLaunchKernelGGL((gemm_kernel<false>), dim3(NR * (HDIM / 64)), blk, 0, stream, Y0,  W4t,  bb[3], aa[3], (void*)Y1, HDIM, HDIM);
  hipLaunchKernelGGL((gemm_kernel<false>), dim3(NR * (HDIM / 64)), blk, 0, stream, Y1,  W5bt, bb[4], aa[4], (void*)Y0, HDIM, HDIM);
  hipLaunchKernelGGL((gemm_kernel<true>),  dim3(NR * (GD / 64)),   blk, 0, stream, Y0,  W6t,  bb[5], nullptr, (void*)gsb, GD, HDIM);

  hipLaunchKernelGGL(final_kernel, dim3(BATCH), dim3(256), 0, stream, gsb, cntb, Ksb, out, K);
}